// Round 1
// baseline (577.504 us; speedup 1.0000x reference)
//
#include <hip/hip_runtime.h>

// Problem constants (fixed by setup_inputs / reference)
#define BN  4       // batch
#define NPT 16384   // points per batch
#define NCC 1024    // FPS centroids
#define KNN 32      // neighbors

// Workspace layout (bytes). Total ~416 KB.
#define OFF_CFLAG   0                         // BN*NPT bytes: point used as centroid?
#define OFF_SFLAG   (BN*NPT)                  // BN*NPT bytes: point selected as neighbor?
#define OFF_CCOUNT  (2*BN*NPT)                // BN ints
#define OFF_SCOUNT  (2*BN*NPT + 64)           // BN ints
#define OFF_POOL    (2*BN*NPT + 128)          // BN*NCC floats (max-pool accumulator)
#define ZERO_BYTES  (OFF_POOL + BN*NCC*4)
#define OFF_CLIST   (ZERO_BYTES)              // BN*NCC ints
#define OFF_SLIST   (OFF_CLIST + BN*NCC*4)    // BN*NPT ints

// ---------------------------------------------------------------------------
// FPS with cycle detection. One block per batch, 1024 threads, 16 pts/thread
// in registers. far_{i+1} = argmax_j ||x_j - x_{far_i}||^2 is a deterministic
// map, so the far sequence cycles; once a repeat is seen the SET of centroids
// (all downstream needs) is complete. Exact reference formula via __f*_rn.
// ---------------------------------------------------------------------------
__global__ __launch_bounds__(1024) void fps_kernel(const float* __restrict__ x,
    const int* __restrict__ far_init, unsigned char* __restrict__ cent_flag)
{
    const int b = blockIdx.x, t = threadIdx.x;
    __shared__ __align__(16) unsigned char seen[NPT];
    __shared__ float rd[16];
    __shared__ int   ri[16];
    __shared__ float cs[3];
    __shared__ int   s_nf, s_done;

    const float* xb = x + (size_t)b * NPT * 3;
    float px[16], py[16], pz[16];
#pragma unroll
    for (int j = 0; j < 16; ++j) {
        int idx = t + (j << 10);
        px[j] = xb[idx*3+0]; py[j] = xb[idx*3+1]; pz[j] = xb[idx*3+2];
    }
    ((uint4*)seen)[t] = make_uint4(0,0,0,0);
    __syncthreads();
    if (t == 0) { int f0 = far_init[b]; seen[f0] = 1; s_nf = f0; s_done = 0; }
    __syncthreads();

    for (int it = 0; it < NCC-1; ++it) {
        int nf = s_nf;
        if (t == (nf & (NPT/16 - 1) & 1023)) { /* owner publishes centroid */ }
        if (t == (nf & 1023)) {
            int j = nf >> 10;
            cs[0] = px[j]; cs[1] = py[j]; cs[2] = pz[j];
        }
        __syncthreads();                       // barrier A: cs visible
        float cx = cs[0], cy = cs[1], cz = cs[2];
        float best = -1.0f; int bi = 0;
#pragma unroll
        for (int j = 0; j < 16; ++j) {
            float dx = __fsub_rn(px[j], cx);
            float dy = __fsub_rn(py[j], cy);
            float dz = __fsub_rn(pz[j], cz);
            float d  = __fadd_rn(__fadd_rn(__fmul_rn(dx,dx), __fmul_rn(dy,dy)),
                                 __fmul_rn(dz,dz));
            int idx = t + (j << 10);           // ascending: strict > keeps first
            if (d > best) { best = d; bi = idx; }
        }
        // wave argmax (64 lanes), tie -> smaller index (jnp.argmax semantics)
#pragma unroll
        for (int m = 1; m < 64; m <<= 1) {
            float od = __shfl_xor(best, m, 64);
            int   oi = __shfl_xor(bi,   m, 64);
            if (od > best || (od == best && oi < bi)) { best = od; bi = oi; }
        }
        if ((t & 63) == 0) { rd[t >> 6] = best; ri[t >> 6] = bi; }
        __syncthreads();
        if (t == 0) {
            float bd = rd[0]; int bx = ri[0];
            for (int k = 1; k < 16; ++k)
                if (rd[k] > bd || (rd[k] == bd && ri[k] < bx)) { bd = rd[k]; bx = ri[k]; }
            if (seen[bx]) s_done = 1;          // cycle: centroid SET complete
            else { seen[bx] = 1; s_nf = bx; }
        }
        __syncthreads();                       // barrier B: s_nf/s_done visible
        if (s_done) break;
    }
    __syncthreads();
    uint4* cf = (uint4*)(cent_flag + (size_t)b * NPT);
    cf[t] = ((const uint4*)seen)[t];
}

// ---------------------------------------------------------------------------
// Compact a byte-flag array [BN][NPT] into per-batch index lists (order-free).
// ---------------------------------------------------------------------------
__global__ void compact_kernel(const unsigned char* __restrict__ flag,
    int* __restrict__ list, int* __restrict__ count, int cap)
{
    int gid = blockIdx.x * blockDim.x + threadIdx.x;
    int b = gid >> 14, i = gid & (NPT - 1);
    if (flag[gid]) {
        int pos = atomicAdd(&count[b], 1);
        if (pos < cap) list[b * cap + pos] = i;
    }
}

// ---------------------------------------------------------------------------
// KNN: per unique centroid, radix-select the exact 32nd-smallest d2 (monotone
// key transform so negative-rounded d2 still orders correctly), then mark all
// points with key <= tau. Keys recomputed per pass (no 64KB LDS needed).
// d2 formula matches reference: |c|^2 + |x|^2 - 2 c.x, fp32, no contraction.
// ---------------------------------------------------------------------------
__device__ __forceinline__ unsigned knn_key(const float* __restrict__ xb, int i,
                                            float cx, float cy, float cz, float cn)
{
    float px = xb[i*3], py = xb[i*3+1], pz = xb[i*3+2];
    float xn  = __fadd_rn(__fadd_rn(__fmul_rn(px,px), __fmul_rn(py,py)), __fmul_rn(pz,pz));
    float dot = __fadd_rn(__fadd_rn(__fmul_rn(cx,px), __fmul_rn(cy,py)), __fmul_rn(cz,pz));
    float d2  = __fsub_rn(__fadd_rn(cn, xn), __fmul_rn(2.0f, dot));
    unsigned u = __float_as_uint(d2);
    return u ^ ((u >> 31) ? 0xFFFFFFFFu : 0x80000000u);
}

__global__ __launch_bounds__(256) void knn_kernel(const float* __restrict__ x,
    const int* __restrict__ cent_list, const int* __restrict__ cent_count,
    unsigned char* __restrict__ selected)
{
    const int b = blockIdx.y, m = blockIdx.x, t = threadIdx.x;
    if (m >= cent_count[b]) return;
    __shared__ unsigned hist[256];
    __shared__ unsigned s_pref, s_rem;

    const float* xb = x + (size_t)b * NPT * 3;
    int ci = cent_list[b * NCC + m];
    float cx = xb[ci*3], cy = xb[ci*3+1], cz = xb[ci*3+2];
    float cn = __fadd_rn(__fadd_rn(__fmul_rn(cx,cx), __fmul_rn(cy,cy)), __fmul_rn(cz,cz));

    if (t == 0) { s_pref = 0u; s_rem = KNN; }
    __syncthreads();

    for (int shift = 24; shift >= 0; shift -= 8) {
        hist[t] = 0u;
        __syncthreads();
        unsigned pref = s_pref;
        for (int j = 0; j < NPT/256; ++j) {
            unsigned k = knn_key(xb, t + (j << 8), cx, cy, cz, cn);
            unsigned hi = (unsigned)(((unsigned long long)k) >> (shift + 8)); // defined for shift=24
            if (hi == pref) atomicAdd(&hist[(k >> shift) & 255u], 1u);
        }
        __syncthreads();
        if (t == 0) {
            unsigned rem = s_rem, cum = 0;
            for (int bin = 0; bin < 256; ++bin) {
                unsigned c2 = cum + hist[bin];
                if (c2 >= rem) { s_pref = (pref << 8) | (unsigned)bin; s_rem = rem - cum; break; }
                cum = c2;
            }
        }
        __syncthreads();
    }
    unsigned tau = s_pref;   // exact key of the 32nd-smallest distance
    unsigned char* sb = selected + (size_t)b * NPT;
    for (int j = 0; j < NPT/256; ++j) {
        int i = t + (j << 8);
        if (knn_key(xb, i, cx, cy, cz, cn) <= tau) sb[i] = 1;
    }
}

// ---------------------------------------------------------------------------
// MLP (3->64->64->64->128->1024, ReLU) on compacted selected points only,
// fused with global max-pool. 64-point tiles, h stored [ch][pt] in LDS
// (conflict-free), weights read uniform-per-wave (scalar loads). The fat
// 128->1024 layer is split across gridDim.z=8 channel groups.
// ---------------------------------------------------------------------------
__global__ __launch_bounds__(256) void mlp_kernel(const float* __restrict__ x,
    const int* __restrict__ sel_list, const int* __restrict__ sel_count,
    const float* __restrict__ w1, const float* __restrict__ b1,
    const float* __restrict__ w2, const float* __restrict__ b2,
    const float* __restrict__ w3, const float* __restrict__ b3,
    const float* __restrict__ w4, const float* __restrict__ b4,
    const float* __restrict__ w5, const float* __restrict__ b5,
    float* __restrict__ pool)
{
    const int b = blockIdx.y, z = blockIdx.z, t = threadIdx.x;
    const int cnt = sel_count[b];
    const int base = blockIdx.x << 6;
    if (base >= cnt) return;
    const int npts = min(64, cnt - base);

    __shared__ float A[128 * 64];   // 32 KB
    __shared__ float Bf[64 * 64];   // 16 KB
    const int p = t & 63, og = t >> 6;

    if (t < 64) {
        int idx = sel_list[b * NPT + base + min(t, npts - 1)];  // clamp dup, masked later
        const float* xp = x + ((size_t)b * NPT + idx) * 3;
        A[t] = xp[0]; A[64 + t] = xp[1]; A[128 + t] = xp[2];
    }
    __syncthreads();
    for (int oc = og; oc < 64; oc += 4) {          // L1: 3->64, A->Bf
        float acc = b1[oc];
#pragma unroll
        for (int k = 0; k < 3; ++k) acc += A[k*64+p] * w1[oc*3+k];
        Bf[oc*64+p] = fmaxf(acc, 0.0f);
    }
    __syncthreads();
    for (int oc = og; oc < 64; oc += 4) {          // L2: 64->64, Bf->A
        float acc = b2[oc];
        for (int k = 0; k < 64; ++k) acc += Bf[k*64+p] * w2[oc*64+k];
        A[oc*64+p] = fmaxf(acc, 0.0f);
    }
    __syncthreads();
    for (int oc = og; oc < 64; oc += 4) {          // L3: 64->64, A->Bf
        float acc = b3[oc];
        for (int k = 0; k < 64; ++k) acc += A[k*64+p] * w3[oc*64+k];
        Bf[oc*64+p] = fmaxf(acc, 0.0f);
    }
    __syncthreads();
    for (int oc = og; oc < 128; oc += 4) {         // L4: 64->128, Bf->A
        float acc = b4[oc];
        for (int k = 0; k < 64; ++k) acc += Bf[k*64+p] * w4[oc*64+k];
        A[oc*64+p] = fmaxf(acc, 0.0f);
    }
    __syncthreads();
    // L5 slice + max-pool: channels [z*128, z*128+128)
    for (int oc = z*128 + og; oc < z*128 + 128; oc += 4) {
        float acc = b5[oc];
        for (int k = 0; k < 128; ++k) acc += A[k*64+p] * w5[oc*128+k];
        float v = (p < npts) ? fmaxf(acc, 0.0f) : 0.0f;  // pad contributes 0 (safe: all >=0)
#pragma unroll
        for (int m = 1; m < 64; m <<= 1) v = fmaxf(v, __shfl_xor(v, m, 64));
        if (p == 0) atomicMax((int*)&pool[b*NCC + oc], __float_as_int(v));
    }
}

// ---------------------------------------------------------------------------
// FC head: 1024 -> 512(relu) -> 256(relu) -> 3. One block per batch.
// ---------------------------------------------------------------------------
__global__ __launch_bounds__(256) void head_kernel(const float* __restrict__ pool,
    const float* __restrict__ fw1, const float* __restrict__ fb1,
    const float* __restrict__ fw2, const float* __restrict__ fb2,
    const float* __restrict__ fw3, const float* __restrict__ fb3,
    float* __restrict__ out)
{
    const int b = blockIdx.x, t = threadIdx.x;
    __shared__ float g[1024], h1[512], h2[256];
    for (int i = t; i < 1024; i += 256) g[i] = pool[b*NCC + i];
    __syncthreads();
    for (int o = t; o < 512; o += 256) {
        float acc = fb1[o];
        for (int k = 0; k < 1024; ++k) acc += g[k] * fw1[o*1024+k];
        h1[o] = fmaxf(acc, 0.0f);
    }
    __syncthreads();
    {
        float acc = fb2[t];
        for (int k = 0; k < 512; ++k) acc += h1[k] * fw2[t*512+k];
        h2[t] = fmaxf(acc, 0.0f);
    }
    __syncthreads();
    if (t < 3) {
        float acc = fb3[t];
        for (int k = 0; k < 256; ++k) acc += h2[k] * fw3[t*256+k];
        out[b*3 + t] = acc;
    }
}

extern "C" void kernel_launch(void* const* d_in, const int* in_sizes, int n_in,
                              void* d_out, int out_size, void* d_ws, size_t ws_size,
                              hipStream_t stream)
{
    const float* x    = (const float*)d_in[0];
    const int*   far0 = (const int*)  d_in[1];
    const float *w1 = (const float*)d_in[2],  *b1 = (const float*)d_in[3];
    const float *w2 = (const float*)d_in[4],  *b2 = (const float*)d_in[5];
    const float *w3 = (const float*)d_in[6],  *b3 = (const float*)d_in[7];
    const float *w4 = (const float*)d_in[8],  *b4 = (const float*)d_in[9];
    const float *w5 = (const float*)d_in[10], *b5 = (const float*)d_in[11];
    const float *fw1 = (const float*)d_in[12], *fb1 = (const float*)d_in[13];
    const float *fw2 = (const float*)d_in[14], *fb2 = (const float*)d_in[15];
    const float *fw3 = (const float*)d_in[16], *fb3 = (const float*)d_in[17];

    char* ws = (char*)d_ws;
    unsigned char* cflag = (unsigned char*)(ws + OFF_CFLAG);
    unsigned char* sflag = (unsigned char*)(ws + OFF_SFLAG);
    int*   ccount = (int*)(ws + OFF_CCOUNT);
    int*   scount = (int*)(ws + OFF_SCOUNT);
    float* pool   = (float*)(ws + OFF_POOL);
    int*   clist  = (int*)(ws + OFF_CLIST);
    int*   slist  = (int*)(ws + OFF_SLIST);

    hipMemsetAsync(d_ws, 0, ZERO_BYTES, stream);  // flags, counts, pool -> 0

    fps_kernel<<<BN, 1024, 0, stream>>>(x, far0, cflag);
    compact_kernel<<<BN*NPT/256, 256, 0, stream>>>(cflag, clist, ccount, NCC);
    knn_kernel<<<dim3(NCC, BN), 256, 0, stream>>>(x, clist, ccount, sflag);
    compact_kernel<<<BN*NPT/256, 256, 0, stream>>>(sflag, slist, scount, NPT);
    mlp_kernel<<<dim3(NPT/64, BN, 8), 256, 0, stream>>>(x, slist, scount,
        w1,b1, w2,b2, w3,b3, w4,b4, w5,b5, pool);
    head_kernel<<<BN, 256, 0, stream>>>(pool, fw1,fb1, fw2,fb2, fw3,fb3, (float*)d_out);
}

// Round 2
// 352.859 us; speedup vs baseline: 1.6366x; 1.6366x over previous
//
#include <hip/hip_runtime.h>

// Problem constants (fixed by setup_inputs / reference)
#define BN  4       // batch
#define NPT 16384   // points per batch
#define NCC 1024    // FPS centroids
#define KNN 32      // neighbors

// Workspace layout (bytes). Total ~416 KB.
#define OFF_CFLAG   0                         // BN*NPT bytes: point used as centroid?
#define OFF_SFLAG   (BN*NPT)                  // BN*NPT bytes: point selected as neighbor?
#define OFF_CCOUNT  (2*BN*NPT)                // BN ints
#define OFF_SCOUNT  (2*BN*NPT + 64)           // BN ints
#define OFF_POOL    (2*BN*NPT + 128)          // BN*NCC floats (max-pool accumulator)
#define ZERO_BYTES  (OFF_POOL + BN*NCC*4)
#define OFF_CLIST   (ZERO_BYTES)              // BN*NCC ints
#define OFF_SLIST   (OFF_CLIST + BN*NCC*4)    // BN*NPT ints

// ---------------------------------------------------------------------------
// FPS with cycle detection (UNCHANGED — proven correct, absmax 0.0).
// ---------------------------------------------------------------------------
__global__ __launch_bounds__(1024) void fps_kernel(const float* __restrict__ x,
    const int* __restrict__ far_init, unsigned char* __restrict__ cent_flag)
{
    const int b = blockIdx.x, t = threadIdx.x;
    __shared__ __align__(16) unsigned char seen[NPT];
    __shared__ float rd[16];
    __shared__ int   ri[16];
    __shared__ float cs[3];
    __shared__ int   s_nf, s_done;

    const float* xb = x + (size_t)b * NPT * 3;
    float px[16], py[16], pz[16];
#pragma unroll
    for (int j = 0; j < 16; ++j) {
        int idx = t + (j << 10);
        px[j] = xb[idx*3+0]; py[j] = xb[idx*3+1]; pz[j] = xb[idx*3+2];
    }
    ((uint4*)seen)[t] = make_uint4(0,0,0,0);
    __syncthreads();
    if (t == 0) { int f0 = far_init[b]; seen[f0] = 1; s_nf = f0; s_done = 0; }
    __syncthreads();

    for (int it = 0; it < NCC-1; ++it) {
        int nf = s_nf;
        if (t == (nf & 1023)) {
            int j = nf >> 10;
            cs[0] = px[j]; cs[1] = py[j]; cs[2] = pz[j];
        }
        __syncthreads();                       // barrier A: cs visible
        float cx = cs[0], cy = cs[1], cz = cs[2];
        float best = -1.0f; int bi = 0;
#pragma unroll
        for (int j = 0; j < 16; ++j) {
            float dx = __fsub_rn(px[j], cx);
            float dy = __fsub_rn(py[j], cy);
            float dz = __fsub_rn(pz[j], cz);
            float d  = __fadd_rn(__fadd_rn(__fmul_rn(dx,dx), __fmul_rn(dy,dy)),
                                 __fmul_rn(dz,dz));
            int idx = t + (j << 10);           // ascending: strict > keeps first
            if (d > best) { best = d; bi = idx; }
        }
        // wave argmax (64 lanes), tie -> smaller index (jnp.argmax semantics)
#pragma unroll
        for (int m = 1; m < 64; m <<= 1) {
            float od = __shfl_xor(best, m, 64);
            int   oi = __shfl_xor(bi,   m, 64);
            if (od > best || (od == best && oi < bi)) { best = od; bi = oi; }
        }
        if ((t & 63) == 0) { rd[t >> 6] = best; ri[t >> 6] = bi; }
        __syncthreads();
        if (t == 0) {
            float bd = rd[0]; int bx = ri[0];
            for (int k = 1; k < 16; ++k)
                if (rd[k] > bd || (rd[k] == bd && ri[k] < bx)) { bd = rd[k]; bx = ri[k]; }
            if (seen[bx]) s_done = 1;          // cycle: centroid SET complete
            else { seen[bx] = 1; s_nf = bx; }
        }
        __syncthreads();                       // barrier B: s_nf/s_done visible
        if (s_done) break;
    }
    __syncthreads();
    uint4* cf = (uint4*)(cent_flag + (size_t)b * NPT);
    cf[t] = ((const uint4*)seen)[t];
}

// ---------------------------------------------------------------------------
// Compact byte flags into per-batch index lists (order-free). UNCHANGED.
// ---------------------------------------------------------------------------
__global__ void compact_kernel(const unsigned char* __restrict__ flag,
    int* __restrict__ list, int* __restrict__ count, int cap)
{
    int gid = blockIdx.x * blockDim.x + threadIdx.x;
    int b = gid >> 14, i = gid & (NPT - 1);
    if (flag[gid]) {
        int pos = atomicAdd(&count[b], 1);
        if (pos < cap) list[b * cap + pos] = i;
    }
}

// ---------------------------------------------------------------------------
// KNN radix-select (UNCHANGED — proven correct).
// ---------------------------------------------------------------------------
__device__ __forceinline__ unsigned knn_key(const float* __restrict__ xb, int i,
                                            float cx, float cy, float cz, float cn)
{
    float px = xb[i*3], py = xb[i*3+1], pz = xb[i*3+2];
    float xn  = __fadd_rn(__fadd_rn(__fmul_rn(px,px), __fmul_rn(py,py)), __fmul_rn(pz,pz));
    float dot = __fadd_rn(__fadd_rn(__fmul_rn(cx,px), __fmul_rn(cy,py)), __fmul_rn(cz,pz));
    float d2  = __fsub_rn(__fadd_rn(cn, xn), __fmul_rn(2.0f, dot));
    unsigned u = __float_as_uint(d2);
    return u ^ ((u >> 31) ? 0xFFFFFFFFu : 0x80000000u);
}

__global__ __launch_bounds__(256) void knn_kernel(const float* __restrict__ x,
    const int* __restrict__ cent_list, const int* __restrict__ cent_count,
    unsigned char* __restrict__ selected)
{
    const int b = blockIdx.y, m = blockIdx.x, t = threadIdx.x;
    if (m >= cent_count[b]) return;
    __shared__ unsigned hist[256];
    __shared__ unsigned s_pref, s_rem;

    const float* xb = x + (size_t)b * NPT * 3;
    int ci = cent_list[b * NCC + m];
    float cx = xb[ci*3], cy = xb[ci*3+1], cz = xb[ci*3+2];
    float cn = __fadd_rn(__fadd_rn(__fmul_rn(cx,cx), __fmul_rn(cy,cy)), __fmul_rn(cz,cz));

    if (t == 0) { s_pref = 0u; s_rem = KNN; }
    __syncthreads();

    for (int shift = 24; shift >= 0; shift -= 8) {
        hist[t] = 0u;
        __syncthreads();
        unsigned pref = s_pref;
        for (int j = 0; j < NPT/256; ++j) {
            unsigned k = knn_key(xb, t + (j << 8), cx, cy, cz, cn);
            unsigned hi = (unsigned)(((unsigned long long)k) >> (shift + 8));
            if (hi == pref) atomicAdd(&hist[(k >> shift) & 255u], 1u);
        }
        __syncthreads();
        if (t == 0) {
            unsigned rem = s_rem, cum = 0;
            for (int bin = 0; bin < 256; ++bin) {
                unsigned c2 = cum + hist[bin];
                if (c2 >= rem) { s_pref = (pref << 8) | (unsigned)bin; s_rem = rem - cum; break; }
                cum = c2;
            }
        }
        __syncthreads();
    }
    unsigned tau = s_pref;   // exact key of the 32nd-smallest distance
    unsigned char* sb = selected + (size_t)b * NPT;
    for (int j = 0; j < NPT/256; ++j) {
        int i = t + (j << 8);
        if (knn_key(xb, i, cx, cy, cz, cn) <= tau) sb[i] = 1;
    }
}

// ---------------------------------------------------------------------------
// MLP v2: 1024 threads (16 waves), z=4 L5-slices of 256 ocs. Wave-uniform
// oc groups via readfirstlane -> all weight reads are scalar (s_load).
// Multiple independent accumulators per thread -> issue-bound, not latency.
// ---------------------------------------------------------------------------
__device__ __forceinline__ void layer64(const float* __restrict__ src,
    float* __restrict__ dst, const float* __restrict__ w,
    const float* __restrict__ bias, int ocb, int p)
{
    float a0 = bias[ocb+0], a1 = bias[ocb+1], a2 = bias[ocb+2], a3 = bias[ocb+3];
#pragma unroll 8
    for (int k = 0; k < 64; ++k) {
        float a = src[k*64+p];
        a0 += a * w[(ocb+0)*64+k];
        a1 += a * w[(ocb+1)*64+k];
        a2 += a * w[(ocb+2)*64+k];
        a3 += a * w[(ocb+3)*64+k];
    }
    dst[(ocb+0)*64+p] = fmaxf(a0, 0.0f);
    dst[(ocb+1)*64+p] = fmaxf(a1, 0.0f);
    dst[(ocb+2)*64+p] = fmaxf(a2, 0.0f);
    dst[(ocb+3)*64+p] = fmaxf(a3, 0.0f);
}

__global__ __launch_bounds__(1024) void mlp_kernel(const float* __restrict__ x,
    const int* __restrict__ sel_list, const int* __restrict__ sel_count,
    const float* __restrict__ w1, const float* __restrict__ b1,
    const float* __restrict__ w2, const float* __restrict__ b2,
    const float* __restrict__ w3, const float* __restrict__ b3,
    const float* __restrict__ w4, const float* __restrict__ b4,
    const float* __restrict__ w5, const float* __restrict__ b5,
    float* __restrict__ pool)
{
    const int b = blockIdx.y, z = blockIdx.z, t = threadIdx.x;
    const int cnt = sel_count[b];
    const int p = t & 63;
    const int wv = __builtin_amdgcn_readfirstlane(t >> 6);  // 0..15, wave-uniform

    __shared__ float A[128 * 64];   // 32 KB
    __shared__ float Bf[64 * 64];   // 16 KB

    for (int base = blockIdx.x << 6; base < cnt; base += (64 << 6)) {
        const int npts = min(64, cnt - base);
        __syncthreads();                        // previous tile's reads done
        if (t < 64) {
            int idx = sel_list[b * NPT + base + min(t, npts - 1)];  // pad = dup last
            const float* xp = x + ((size_t)b * NPT + idx) * 3;
            A[t] = xp[0]; A[64 + t] = xp[1]; A[128 + t] = xp[2];
        }
        __syncthreads();
        // L1: 3->64, A(rows0..2) -> Bf. 4 ocs/wave.
        {
            float a0 = A[p], a1 = A[64 + p], a2 = A[128 + p];
            int ocb = wv * 4;
#pragma unroll
            for (int i = 0; i < 4; ++i) {
                int oc = ocb + i;
                float acc = b1[oc] + a0 * w1[oc*3+0] + a1 * w1[oc*3+1] + a2 * w1[oc*3+2];
                Bf[oc*64+p] = fmaxf(acc, 0.0f);
            }
        }
        __syncthreads();
        layer64(Bf, A, w2, b2, wv * 4, p);      // L2: 64->64
        __syncthreads();
        layer64(A, Bf, w3, b3, wv * 4, p);      // L3: 64->64
        __syncthreads();
        // L4: 64->128, Bf -> A. 8 ocs/wave.
        {
            int ocb = wv * 8;
            float acc[8];
#pragma unroll
            for (int i = 0; i < 8; ++i) acc[i] = b4[ocb + i];
#pragma unroll 4
            for (int k = 0; k < 64; ++k) {
                float a = Bf[k*64+p];
#pragma unroll
                for (int i = 0; i < 8; ++i) acc[i] += a * w4[(ocb+i)*64+k];
            }
#pragma unroll
            for (int i = 0; i < 8; ++i) A[(ocb+i)*64+p] = fmaxf(acc[i], 0.0f);
        }
        __syncthreads();
        // L5 slice + max-pool: ocs [z*256 + wv*16, +16), k over 128.
        {
            int ocb = z * 256 + wv * 16;
            float acc[16];
#pragma unroll
            for (int i = 0; i < 16; ++i) acc[i] = b5[ocb + i];
#pragma unroll 4
            for (int k = 0; k < 128; ++k) {
                float a = A[k*64+p];
#pragma unroll
                for (int i = 0; i < 16; ++i) acc[i] += a * w5[(ocb+i)*128+k];
            }
#pragma unroll
            for (int i = 0; i < 16; ++i) {
                float v = (p < npts) ? fmaxf(acc[i], 0.0f) : 0.0f;  // pad -> 0 (safe: relu>=0)
#pragma unroll
                for (int m = 1; m < 64; m <<= 1) v = fmaxf(v, __shfl_xor(v, m, 64));
                if (p == 0) atomicMax((int*)&pool[b*NCC + ocb + i], __float_as_int(v));
            }
        }
    }
}

// ---------------------------------------------------------------------------
// FC head v2: wave-per-output, lanes split K (coalesced weight reads),
// butterfly-sum reduce. One 1024-thread block per batch.
// ---------------------------------------------------------------------------
__global__ __launch_bounds__(1024) void head_kernel(const float* __restrict__ pool,
    const float* __restrict__ fw1, const float* __restrict__ fb1,
    const float* __restrict__ fw2, const float* __restrict__ fb2,
    const float* __restrict__ fw3, const float* __restrict__ fb3,
    float* __restrict__ out)
{
    const int b = blockIdx.x, t = threadIdx.x;
    const int l = t & 63;
    const int wv = __builtin_amdgcn_readfirstlane(t >> 6);  // 0..15
    __shared__ float g[1024], h1[512], h2[256];
    g[t] = pool[b*NCC + t];
    __syncthreads();
    // FC1: 1024 -> 512 relu. 32 outputs per wave.
    for (int o = wv; o < 512; o += 16) {
        float acc = 0.0f;
#pragma unroll
        for (int j = 0; j < 16; ++j) {
            int k = l + (j << 6);
            acc += g[k] * fw1[o*1024 + k];
        }
#pragma unroll
        for (int m = 1; m < 64; m <<= 1) acc += __shfl_xor(acc, m, 64);
        if (l == 0) h1[o] = fmaxf(acc + fb1[o], 0.0f);
    }
    __syncthreads();
    // FC2: 512 -> 256 relu. 16 outputs per wave.
    for (int o = wv; o < 256; o += 16) {
        float acc = 0.0f;
#pragma unroll
        for (int j = 0; j < 8; ++j) {
            int k = l + (j << 6);
            acc += h1[k] * fw2[o*512 + k];
        }
#pragma unroll
        for (int m = 1; m < 64; m <<= 1) acc += __shfl_xor(acc, m, 64);
        if (l == 0) h2[o] = fmaxf(acc + fb2[o], 0.0f);
    }
    __syncthreads();
    // FC3: 256 -> 3 (no relu). Waves 0..2.
    if (wv < 3) {
        float acc = 0.0f;
#pragma unroll
        for (int j = 0; j < 4; ++j) {
            int k = l + (j << 6);
            acc += h2[k] * fw3[wv*256 + k];
        }
#pragma unroll
        for (int m = 1; m < 64; m <<= 1) acc += __shfl_xor(acc, m, 64);
        if (l == 0) out[b*3 + wv] = acc + fb3[wv];
    }
}

extern "C" void kernel_launch(void* const* d_in, const int* in_sizes, int n_in,
                              void* d_out, int out_size, void* d_ws, size_t ws_size,
                              hipStream_t stream)
{
    const float* x    = (const float*)d_in[0];
    const int*   far0 = (const int*)  d_in[1];
    const float *w1 = (const float*)d_in[2],  *b1 = (const float*)d_in[3];
    const float *w2 = (const float*)d_in[4],  *b2 = (const float*)d_in[5];
    const float *w3 = (const float*)d_in[6],  *b3 = (const float*)d_in[7];
    const float *w4 = (const float*)d_in[8],  *b4 = (const float*)d_in[9];
    const float *w5 = (const float*)d_in[10], *b5 = (const float*)d_in[11];
    const float *fw1 = (const float*)d_in[12], *fb1 = (const float*)d_in[13];
    const float *fw2 = (const float*)d_in[14], *fb2 = (const float*)d_in[15];
    const float *fw3 = (const float*)d_in[16], *fb3 = (const float*)d_in[17];

    char* ws = (char*)d_ws;
    unsigned char* cflag = (unsigned char*)(ws + OFF_CFLAG);
    unsigned char* sflag = (unsigned char*)(ws + OFF_SFLAG);
    int*   ccount = (int*)(ws + OFF_CCOUNT);
    int*   scount = (int*)(ws + OFF_SCOUNT);
    float* pool   = (float*)(ws + OFF_POOL);
    int*   clist  = (int*)(ws + OFF_CLIST);
    int*   slist  = (int*)(ws + OFF_SLIST);

    hipMemsetAsync(d_ws, 0, ZERO_BYTES, stream);  // flags, counts, pool -> 0

    fps_kernel<<<BN, 1024, 0, stream>>>(x, far0, cflag);
    compact_kernel<<<BN*NPT/256, 256, 0, stream>>>(cflag, clist, ccount, NCC);
    knn_kernel<<<dim3(NCC, BN), 256, 0, stream>>>(x, clist, ccount, sflag);
    compact_kernel<<<BN*NPT/256, 256, 0, stream>>>(sflag, slist, scount, NPT);
    mlp_kernel<<<dim3(64, BN, 4), 1024, 0, stream>>>(x, slist, scount,
        w1,b1, w2,b2, w3,b3, w4,b4, w5,b5, pool);
    head_kernel<<<BN, 1024, 0, stream>>>(pool, fw1,fb1, fw2,fb2, fw3,fb3, (float*)d_out);
}

// Round 3
// 224.176 us; speedup vs baseline: 2.5761x; 1.5740x over previous
//
#include <hip/hip_runtime.h>

// Problem constants (fixed by setup_inputs / reference)
#define BN  4       // batch
#define NPT 16384   // points per batch
#define NCC 1024    // FPS centroids (cap on unique orbit length)
#define KNN 32      // neighbors

// KNN select parameters
#define HBINS    2048   // 11-bit level-1 histogram
#define CCH      8      // centroids processed per chunk
#define CAND_CAP 768    // boundary-bin candidate cap (overflow -> exact drill)

// Workspace layout (bytes). Total ~305 KB (<= proven-available 416 KB).
#define OFF_CCOUNT 0                          // BN ints
#define OFF_SCOUNT 64                         // BN ints
#define OFF_SBITS  128                        // BN*(NPT/32) u32 = 8 KB
#define OFF_POOL   (128 + BN*(NPT/32)*4)      // BN*NCC floats = 16 KB
#define ZERO_BYTES (OFF_POOL + BN*NCC*4)
#define OFF_CLIST  ZERO_BYTES                 // BN*NCC ints = 16 KB
#define OFF_H1     (OFF_CLIST + BN*NCC*4)     // BN*512 floats = 8 KB
#define OFF_SLIST  (OFF_H1 + BN*512*4)        // BN*NPT ints = 256 KB

// ---------------------------------------------------------------------------
// FPS with cycle detection (core proven, absmax 0.0). Now writes the unique
// centroid index list directly (replaces compact kernel #1).
// ---------------------------------------------------------------------------
__global__ __launch_bounds__(1024) void fps_kernel(const float* __restrict__ x,
    const int* __restrict__ far_init, int* __restrict__ clist, int* __restrict__ ccount)
{
    const int b = blockIdx.x, t = threadIdx.x;
    __shared__ __align__(16) unsigned char seen[NPT];
    __shared__ float rd[16];
    __shared__ int   ri[16];
    __shared__ float cs[3];
    __shared__ int   s_nf, s_done;

    const float* xb = x + (size_t)b * NPT * 3;
    float px[16], py[16], pz[16];
#pragma unroll
    for (int j = 0; j < 16; ++j) {
        int idx = t + (j << 10);
        px[j] = xb[idx*3+0]; py[j] = xb[idx*3+1]; pz[j] = xb[idx*3+2];
    }
    ((uint4*)seen)[t] = make_uint4(0,0,0,0);
    __syncthreads();
    if (t == 0) { int f0 = far_init[b]; seen[f0] = 1; s_nf = f0; s_done = 0; }
    __syncthreads();

    for (int it = 0; it < NCC-1; ++it) {
        int nf = s_nf;
        if (t == (nf & 1023)) {
            int j = nf >> 10;
            cs[0] = px[j]; cs[1] = py[j]; cs[2] = pz[j];
        }
        __syncthreads();                       // barrier A: cs visible
        float cx = cs[0], cy = cs[1], cz = cs[2];
        float best = -1.0f; int bi = 0;
#pragma unroll
        for (int j = 0; j < 16; ++j) {
            float dx = __fsub_rn(px[j], cx);
            float dy = __fsub_rn(py[j], cy);
            float dz = __fsub_rn(pz[j], cz);
            float d  = __fadd_rn(__fadd_rn(__fmul_rn(dx,dx), __fmul_rn(dy,dy)),
                                 __fmul_rn(dz,dz));
            int idx = t + (j << 10);           // ascending: strict > keeps first
            if (d > best) { best = d; bi = idx; }
        }
        // wave argmax (64 lanes), tie -> smaller index (jnp.argmax semantics)
#pragma unroll
        for (int m = 1; m < 64; m <<= 1) {
            float od = __shfl_xor(best, m, 64);
            int   oi = __shfl_xor(bi,   m, 64);
            if (od > best || (od == best && oi < bi)) { best = od; bi = oi; }
        }
        if ((t & 63) == 0) { rd[t >> 6] = best; ri[t >> 6] = bi; }
        __syncthreads();
        if (t == 0) {
            float bd = rd[0]; int bx = ri[0];
            for (int k = 1; k < 16; ++k)
                if (rd[k] > bd || (rd[k] == bd && ri[k] < bx)) { bd = rd[k]; bx = ri[k]; }
            if (seen[bx]) s_done = 1;          // cycle: centroid SET complete
            else { seen[bx] = 1; s_nf = bx; }
        }
        __syncthreads();                       // barrier B: s_nf/s_done visible
        if (s_done) break;
    }
    __syncthreads();
    // Emit unique-centroid list (order-free; downstream is set-invariant).
#pragma unroll
    for (int j = 0; j < 16; ++j) {
        int idx = t + (j << 10);
        if (seen[idx]) {
            int pos = atomicAdd(&ccount[b], 1);
            clist[b * NCC + pos] = idx;
        }
    }
}

// ---------------------------------------------------------------------------
// KNN fused: one block per batch, all centroids per chunk in shared sweeps.
// Exact 32nd-smallest key per centroid (same key transform as proven radix),
// then union-mark + compacted list build via bitmask dedupe.
// ---------------------------------------------------------------------------
__device__ __forceinline__ unsigned key_of(float px, float py, float pz, float xn,
                                           float cx, float cy, float cz, float cn)
{
    float dot = __fadd_rn(__fadd_rn(__fmul_rn(cx,px), __fmul_rn(cy,py)), __fmul_rn(cz,pz));
    float d2  = __fsub_rn(__fadd_rn(cn, xn), __fmul_rn(2.0f, dot));
    unsigned u = __float_as_uint(d2);
    return u ^ ((u >> 31) ? 0xFFFFFFFFu : 0x80000000u);
}

// All 64 lanes of ONE wave call this; single lane writes {bin, below} to LDS.
__device__ __forceinline__ void wave_scan_bins(const unsigned* __restrict__ H,
    int nbins, int rem, int lane, int* __restrict__ out_bin, int* __restrict__ out_below)
{
    int per = nbins >> 6;
    int base = lane * per;
    unsigned part = 0;
    for (int q = 0; q < per; ++q) part += H[base + q];
    unsigned inc = part;
#pragma unroll
    for (int m = 1; m < 64; m <<= 1) {
        unsigned u = __shfl_up(inc, m, 64);
        if (lane >= m) inc += u;
    }
    unsigned exc = inc - part;
    unsigned long long mk = __ballot(exc < (unsigned)rem && inc >= (unsigned)rem);
    int src = __ffsll((long long)mk) - 1;
    if (lane == src) {
        unsigned run = exc; int bb = base;
        for (int q = 0; q < per; ++q) {
            unsigned h = H[base + q];
            if (run + h >= (unsigned)rem) { bb = base + q; break; }
            run += h;
        }
        *out_bin = bb; *out_below = (int)run;
    }
}

__global__ __launch_bounds__(1024) void knn_kernel(const float* __restrict__ x,
    const int* __restrict__ clist, const int* __restrict__ ccount,
    unsigned* __restrict__ sbits, int* __restrict__ slist, int* __restrict__ scount)
{
    const int b = blockIdx.x, t = threadIdx.x;
    const int lane = t & 63, w = t >> 6;
    const int cnt = ccount[b];
    const float* xb = x + (size_t)b * NPT * 3;

    __shared__ unsigned hist[CCH * HBINS];     // 64 KB
    __shared__ unsigned cand[CCH * CAND_CAP];  // 24 KB
    __shared__ float cpx[CCH], cpy[CCH], cpz[CCH], cpn[CCH];
    __shared__ unsigned candCnt[CCH];
    __shared__ int s_bb[CCH], s_below[CCH], s_rrem[CCH], s_need[CCH], s_pref[CCH];
    __shared__ unsigned s_tau[CCH];
    __shared__ int s_tbin, s_tbelow;

    for (int cbase = 0; cbase < cnt; cbase += CCH) {
        const int nc = min(CCH, cnt - cbase);
        __syncthreads();                       // protect LDS reuse across chunks
        if (t < nc) {
            int ci = clist[b * NCC + cbase + t];
            float cx = xb[ci*3], cy = xb[ci*3+1], cz = xb[ci*3+2];
            cpx[t] = cx; cpy[t] = cy; cpz[t] = cz;
            cpn[t] = __fadd_rn(__fadd_rn(__fmul_rn(cx,cx), __fmul_rn(cy,cy)), __fmul_rn(cz,cz));
            candCnt[t] = 0;
        }
        for (int i = t; i < CCH * HBINS; i += 1024) hist[i] = 0;
        __syncthreads();

        // Sweep 1: level-1 histograms (top 11 bits), all centroids at once.
        for (int j = 0; j < NPT/1024; ++j) {
            int i = t + (j << 10);
            float px = xb[i*3], py = xb[i*3+1], pz = xb[i*3+2];
            float xn = __fadd_rn(__fadd_rn(__fmul_rn(px,px), __fmul_rn(py,py)), __fmul_rn(pz,pz));
#pragma unroll
            for (int c = 0; c < CCH; ++c) {
                if (c < nc) {
                    unsigned key = key_of(px,py,pz,xn, cpx[c],cpy[c],cpz[c],cpn[c]);
                    atomicAdd(&hist[c*HBINS + (key >> 21)], 1u);
                }
            }
        }
        __syncthreads();

        // Per-wave selection: wave w finds boundary bin for centroid w.
        if (w < nc)
            wave_scan_bins(&hist[w*HBINS], HBINS, KNN, lane, &s_bb[w], &s_below[w]);
        __syncthreads();
        if (t < nc) s_rrem[t] = KNN - s_below[t];
        __syncthreads();

        // Sweep 2: collect candidate keys in each centroid's boundary bin.
        for (int j = 0; j < NPT/1024; ++j) {
            int i = t + (j << 10);
            float px = xb[i*3], py = xb[i*3+1], pz = xb[i*3+2];
            float xn = __fadd_rn(__fadd_rn(__fmul_rn(px,px), __fmul_rn(py,py)), __fmul_rn(pz,pz));
#pragma unroll
            for (int c = 0; c < CCH; ++c) {
                if (c < nc) {
                    unsigned key = key_of(px,py,pz,xn, cpx[c],cpy[c],cpz[c],cpn[c]);
                    if ((int)(key >> 21) == s_bb[c]) {
                        unsigned pos = atomicAdd(&candCnt[c], 1u);
                        if (pos < CAND_CAP) cand[c*CAND_CAP + pos] = key;
                    }
                }
            }
        }
        __syncthreads();

        // Exact tau: rank-select (rrem-th smallest, with-multiplicity) per wave.
        if (w < nc) {
            unsigned cc = candCnt[w];
            if (cc <= CAND_CAP) {
                int r = s_rrem[w] - 1;
                const unsigned* C = &cand[w*CAND_CAP];
                for (int idx = lane; idx < (int)cc; idx += 64) {
                    unsigned k = C[idx]; int rank = 0;
                    for (int q = 0; q < (int)cc; ++q) {
                        unsigned kq = C[q];
                        rank += (kq < k || (kq == k && q < idx)) ? 1 : 0;
                    }
                    if (rank == r) s_tau[w] = k;   // exactly one idx matches
                }
                if (lane == 0) s_need[w] = 0;
            } else if (lane == 0) s_need[w] = 1;
        }
        __syncthreads();

        // Rare exact drill-down for overflowed boundary bins (guaranteed exact).
        for (int c = 0; c < nc; ++c) {
            if (s_need[c]) {                   // uniform (LDS broadcast)
                const float cx = cpx[c], cy = cpy[c], cz = cpz[c], cn = cpn[c];
                // level 2: bits [10,21)
                for (int i = t; i < HBINS; i += 1024) hist[i] = 0;
                __syncthreads();
                for (int j = 0; j < NPT/1024; ++j) {
                    int i = t + (j << 10);
                    float px = xb[i*3], py = xb[i*3+1], pz = xb[i*3+2];
                    float xn = __fadd_rn(__fadd_rn(__fmul_rn(px,px), __fmul_rn(py,py)), __fmul_rn(pz,pz));
                    unsigned key = key_of(px,py,pz,xn, cx,cy,cz,cn);
                    if ((int)(key >> 21) == s_bb[c]) atomicAdd(&hist[(key >> 10) & 2047u], 1u);
                }
                __syncthreads();
                if (w == 0) wave_scan_bins(hist, HBINS, s_rrem[c], lane, &s_tbin, &s_tbelow);
                __syncthreads();
                if (t == 0) { s_pref[c] = (s_bb[c] << 11) | s_tbin; s_rrem[c] -= s_tbelow; }
                __syncthreads();
                // level 3: bits [0,10) -> bin IS the exact remaining key bits
                for (int i = t; i < 1024; i += 1024) hist[i] = 0;
                __syncthreads();
                for (int j = 0; j < NPT/1024; ++j) {
                    int i = t + (j << 10);
                    float px = xb[i*3], py = xb[i*3+1], pz = xb[i*3+2];
                    float xn = __fadd_rn(__fadd_rn(__fmul_rn(px,px), __fmul_rn(py,py)), __fmul_rn(pz,pz));
                    unsigned key = key_of(px,py,pz,xn, cx,cy,cz,cn);
                    if ((int)(key >> 10) == s_pref[c]) atomicAdd(&hist[key & 1023u], 1u);
                }
                __syncthreads();
                if (w == 0) wave_scan_bins(hist, 1024, s_rrem[c], lane, &s_tbin, &s_tbelow);
                __syncthreads();
                if (t == 0) s_tau[c] = (((unsigned)s_pref[c]) << 10) | (unsigned)s_tbin;
                __syncthreads();
            }
        }
        __syncthreads();                       // s_tau visible to all

        // Sweep 3: union-mark (key <= tau) + build compacted list (deduped).
        for (int j = 0; j < NPT/1024; ++j) {
            int i = t + (j << 10);
            float px = xb[i*3], py = xb[i*3+1], pz = xb[i*3+2];
            float xn = __fadd_rn(__fadd_rn(__fmul_rn(px,px), __fmul_rn(py,py)), __fmul_rn(pz,pz));
            bool sel = false;
#pragma unroll
            for (int c = 0; c < CCH; ++c) {
                if (c < nc) {
                    unsigned key = key_of(px,py,pz,xn, cpx[c],cpy[c],cpz[c],cpn[c]);
                    sel |= (key <= s_tau[c]);
                }
            }
            if (sel) {
                unsigned bit = 1u << (i & 31);
                unsigned old = atomicOr(&sbits[b*(NPT/32) + (i >> 5)], bit);
                if (!(old & bit)) {
                    int pos = atomicAdd(&scount[b], 1);
                    slist[b * NPT + pos] = i;
                }
            }
        }
    }
}

// ---------------------------------------------------------------------------
// MLP on selected points + fused global max-pool (proven v2 structure).
// ---------------------------------------------------------------------------
__device__ __forceinline__ void layer64(const float* __restrict__ src,
    float* __restrict__ dst, const float* __restrict__ w,
    const float* __restrict__ bias, int ocb, int p)
{
    float a0 = bias[ocb+0], a1 = bias[ocb+1], a2 = bias[ocb+2], a3 = bias[ocb+3];
#pragma unroll 8
    for (int k = 0; k < 64; ++k) {
        float a = src[k*64+p];
        a0 += a * w[(ocb+0)*64+k];
        a1 += a * w[(ocb+1)*64+k];
        a2 += a * w[(ocb+2)*64+k];
        a3 += a * w[(ocb+3)*64+k];
    }
    dst[(ocb+0)*64+p] = fmaxf(a0, 0.0f);
    dst[(ocb+1)*64+p] = fmaxf(a1, 0.0f);
    dst[(ocb+2)*64+p] = fmaxf(a2, 0.0f);
    dst[(ocb+3)*64+p] = fmaxf(a3, 0.0f);
}

__global__ __launch_bounds__(1024) void mlp_kernel(const float* __restrict__ x,
    const int* __restrict__ sel_list, const int* __restrict__ sel_count,
    const float* __restrict__ w1, const float* __restrict__ b1,
    const float* __restrict__ w2, const float* __restrict__ b2,
    const float* __restrict__ w3, const float* __restrict__ b3,
    const float* __restrict__ w4, const float* __restrict__ b4,
    const float* __restrict__ w5, const float* __restrict__ b5,
    float* __restrict__ pool)
{
    const int b = blockIdx.y, z = blockIdx.z, t = threadIdx.x;
    const int cnt = sel_count[b];
    const int p = t & 63;
    const int wv = __builtin_amdgcn_readfirstlane(t >> 6);  // 0..15, wave-uniform

    __shared__ float A[128 * 64];   // 32 KB
    __shared__ float Bf[64 * 64];   // 16 KB

    for (int base = blockIdx.x << 6; base < cnt; base += (16 << 6)) {
        const int npts = min(64, cnt - base);
        __syncthreads();                        // previous tile's reads done
        if (t < 64) {
            int idx = sel_list[b * NPT + base + min(t, npts - 1)];  // pad = dup last
            const float* xp = x + ((size_t)b * NPT + idx) * 3;
            A[t] = xp[0]; A[64 + t] = xp[1]; A[128 + t] = xp[2];
        }
        __syncthreads();
        {   // L1: 3->64
            float a0 = A[p], a1 = A[64 + p], a2 = A[128 + p];
            int ocb = wv * 4;
#pragma unroll
            for (int i = 0; i < 4; ++i) {
                int oc = ocb + i;
                float acc = b1[oc] + a0 * w1[oc*3+0] + a1 * w1[oc*3+1] + a2 * w1[oc*3+2];
                Bf[oc*64+p] = fmaxf(acc, 0.0f);
            }
        }
        __syncthreads();
        layer64(Bf, A, w2, b2, wv * 4, p);      // L2: 64->64
        __syncthreads();
        layer64(A, Bf, w3, b3, wv * 4, p);      // L3: 64->64
        __syncthreads();
        {   // L4: 64->128
            int ocb = wv * 8;
            float acc[8];
#pragma unroll
            for (int i = 0; i < 8; ++i) acc[i] = b4[ocb + i];
#pragma unroll 4
            for (int k = 0; k < 64; ++k) {
                float a = Bf[k*64+p];
#pragma unroll
                for (int i = 0; i < 8; ++i) acc[i] += a * w4[(ocb+i)*64+k];
            }
#pragma unroll
            for (int i = 0; i < 8; ++i) A[(ocb+i)*64+p] = fmaxf(acc[i], 0.0f);
        }
        __syncthreads();
        {   // L5 slice + max-pool
            int ocb = z * 256 + wv * 16;
            float acc[16];
#pragma unroll
            for (int i = 0; i < 16; ++i) acc[i] = b5[ocb + i];
#pragma unroll 4
            for (int k = 0; k < 128; ++k) {
                float a = A[k*64+p];
#pragma unroll
                for (int i = 0; i < 16; ++i) acc[i] += a * w5[(ocb+i)*128+k];
            }
#pragma unroll
            for (int i = 0; i < 16; ++i) {
                float v = (p < npts) ? fmaxf(acc[i], 0.0f) : 0.0f;  // pad -> 0 (relu>=0)
#pragma unroll
                for (int m = 1; m < 64; m <<= 1) v = fmaxf(v, __shfl_xor(v, m, 64));
                if (p == 0) atomicMax((int*)&pool[b*NCC + ocb + i], __float_as_int(v));
            }
        }
    }
}

// ---------------------------------------------------------------------------
// FC head, split for parallelism. head1: FC1 (1024->512 relu), 4 blocks/batch.
// ---------------------------------------------------------------------------
__global__ __launch_bounds__(1024) void head1_kernel(const float* __restrict__ pool,
    const float* __restrict__ fw1, const float* __restrict__ fb1,
    float* __restrict__ h1g)
{
    const int bo = blockIdx.x, b = blockIdx.y, t = threadIdx.x;
    const int lane = t & 63, w = t >> 6;
    __shared__ float g[1024];
    g[t] = pool[b*NCC + t];
    __syncthreads();
    int o = bo * 128 + w * 8;
#pragma unroll
    for (int i = 0; i < 8; ++i, ++o) {
        float acc = 0.0f;
#pragma unroll
        for (int j = 0; j < 16; ++j) {
            int k = lane + (j << 6);
            acc += g[k] * fw1[o*1024 + k];
        }
#pragma unroll
        for (int m = 1; m < 64; m <<= 1) acc += __shfl_xor(acc, m, 64);
        if (lane == 0) h1g[b*512 + o] = fmaxf(acc + fb1[o], 0.0f);
    }
}

// head2: FC2 (512->256 relu) + FC3 (256->3). One block per batch.
__global__ __launch_bounds__(1024) void head2_kernel(const float* __restrict__ h1g,
    const float* __restrict__ fw2, const float* __restrict__ fb2,
    const float* __restrict__ fw3, const float* __restrict__ fb3,
    float* __restrict__ out)
{
    const int b = blockIdx.x, t = threadIdx.x;
    const int lane = t & 63, w = t >> 6;
    __shared__ float h1[512], h2[256];
    if (t < 512) h1[t] = h1g[b*512 + t];
    __syncthreads();
#pragma unroll
    for (int i = 0; i < 16; ++i) {
        int o = w * 16 + i;
        float acc = 0.0f;
#pragma unroll
        for (int j = 0; j < 8; ++j) {
            int k = lane + (j << 6);
            acc += h1[k] * fw2[o*512 + k];
        }
#pragma unroll
        for (int m = 1; m < 64; m <<= 1) acc += __shfl_xor(acc, m, 64);
        if (lane == 0) h2[o] = fmaxf(acc + fb2[o], 0.0f);
    }
    __syncthreads();
    if (w < 3) {
        float acc = 0.0f;
#pragma unroll
        for (int j = 0; j < 4; ++j) {
            int k = lane + (j << 6);
            acc += h2[k] * fw3[w*256 + k];
        }
#pragma unroll
        for (int m = 1; m < 64; m <<= 1) acc += __shfl_xor(acc, m, 64);
        if (lane == 0) out[b*3 + w] = acc + fb3[w];
    }
}

extern "C" void kernel_launch(void* const* d_in, const int* in_sizes, int n_in,
                              void* d_out, int out_size, void* d_ws, size_t ws_size,
                              hipStream_t stream)
{
    const float* x    = (const float*)d_in[0];
    const int*   far0 = (const int*)  d_in[1];
    const float *w1 = (const float*)d_in[2],  *b1 = (const float*)d_in[3];
    const float *w2 = (const float*)d_in[4],  *b2 = (const float*)d_in[5];
    const float *w3 = (const float*)d_in[6],  *b3 = (const float*)d_in[7];
    const float *w4 = (const float*)d_in[8],  *b4 = (const float*)d_in[9];
    const float *w5 = (const float*)d_in[10], *b5 = (const float*)d_in[11];
    const float *fw1 = (const float*)d_in[12], *fb1 = (const float*)d_in[13];
    const float *fw2 = (const float*)d_in[14], *fb2 = (const float*)d_in[15];
    const float *fw3 = (const float*)d_in[16], *fb3 = (const float*)d_in[17];

    char* ws = (char*)d_ws;
    int*      ccount = (int*)     (ws + OFF_CCOUNT);
    int*      scount = (int*)     (ws + OFF_SCOUNT);
    unsigned* sbits  = (unsigned*)(ws + OFF_SBITS);
    float*    pool   = (float*)   (ws + OFF_POOL);
    int*      clist  = (int*)     (ws + OFF_CLIST);
    float*    h1g    = (float*)   (ws + OFF_H1);
    int*      slist  = (int*)     (ws + OFF_SLIST);

    hipMemsetAsync(d_ws, 0, ZERO_BYTES, stream);  // counts, sbits, pool -> 0

    fps_kernel<<<BN, 1024, 0, stream>>>(x, far0, clist, ccount);
    knn_kernel<<<BN, 1024, 0, stream>>>(x, clist, ccount, sbits, slist, scount);
    mlp_kernel<<<dim3(16, BN, 4), 1024, 0, stream>>>(x, slist, scount,
        w1,b1, w2,b2, w3,b3, w4,b4, w5,b5, pool);
    head1_kernel<<<dim3(4, BN), 1024, 0, stream>>>(pool, fw1, fb1, h1g);
    head2_kernel<<<BN, 1024, 0, stream>>>(h1g, fw2,fb2, fw3,fb3, (float*)d_out);
}